// Round 14
// baseline (375.942 us; speedup 1.0000x reference)
//
#include <hip/hip_runtime.h>
#include <hip/hip_bf16.h>
#include <cmath>

// Problem constants
#define B_   8
#define N_   4096
#define DIN1 64
#define DHID 128
#define DOUT2 64
#define MAXDEG 256

template <int SH>
__device__ __forceinline__ float dpp_shr_add(float p) {
    int t = __builtin_amdgcn_update_dpp(0, __float_as_int(p),
                                        0x110 | SH, 0xF, 0xF, true);
    return p + __int_as_float(t);
}
// Row-sum lands on the TOP lane of each GRPL-lane subgroup (row_shr moves
// values toward higher lanes; tops of 8-lane halves stay uncontaminated).
template <int GRPL>
__device__ __forceinline__ float dpp_reduce(float p) {
    if constexpr (GRPL == 16) p = dpp_shr_add<8>(p);
    p = dpp_shr_add<4>(p);
    p = dpp_shr_add<2>(p);
    p = dpp_shr_add<1>(p);
    return p;   // valid on lane GRPL-1 of each subgroup
}

// ---------------------------------------------------------------------------
// Kernel A: role-split fused dispatch.
//   blocks [0, N_/4):            ballot-CSR (wave per row, no LDS use)
//   blocks [N_/4, N_/4 + BN/32): register-tiled linear1 (needs sWt LDS)
// The two roles are data-independent (graph vs flow_x/W1) and roofline-
// complementary (HBM-bound vs VALU-bound) -> they overlap on the device.
// ---------------------------------------------------------------------------
template <int DIN, int DOUT>
__global__ __launch_bounds__(256) void k_csr_linear(
    const float* __restrict__ graph, int* __restrict__ cnt, int* __restrict__ idx,
    const float* __restrict__ x, const float* __restrict__ W,
    float* __restrict__ out)
{
    __shared__ float sWt[DIN][DOUT + 4];
    const int t = threadIdx.x;

    if (blockIdx.x < N_ / 4) {
        // ---- CSR role ----
        const int wave = t >> 6;
        const int lane = t & 63;
        const int n = blockIdx.x * 4 + wave;
        const unsigned long long below_mask = (1ULL << lane) - 1ULL;
        const float4* __restrict__ row4 = (const float4*)(graph + (size_t)n * N_);
        int* __restrict__ myidx = idx + (size_t)n * MAXDEG;
        int base = 0;
        for (int it = 0; it < N_ / 256; ++it) {
            const int i4 = it * 64 + lane;
            float4 g = row4[i4];
            const int e = 4 * i4;
#pragma unroll
            for (int c = 0; c < 4; ++c) {
                const float gc = (c == 0) ? g.x : (c == 1) ? g.y : (c == 2) ? g.z : g.w;
                const unsigned long long mk = __ballot(gc != 0.0f);
                const int pos = base + __popcll(mk & below_mask);
                if (gc != 0.0f && pos < MAXDEG) myidx[pos] = e + c;
                base += __popcll(mk);
            }
        }
        if (lane == 0) cnt[n] = (base < MAXDEG) ? base : MAXDEG;
        return;
    }

    // ---- linear role ----
    constexpr int CG = DOUT / 4;
    constexpr int RG = 256 / CG;
    constexpr int TR = 32 / RG;
    const int lb = blockIdx.x - N_ / 4;

    const float4* W4 = (const float4*)W;
    for (int i = t; i < DOUT * (DIN / 4); i += 256) {
        int kk = i / (DIN / 4);
        int d4 = i % (DIN / 4);
        float4 w = W4[i];
        sWt[4 * d4 + 0][kk] = w.x;
        sWt[4 * d4 + 1][kk] = w.y;
        sWt[4 * d4 + 2][kk] = w.z;
        sWt[4 * d4 + 3][kk] = w.w;
    }
    __syncthreads();

    const int rg = t / CG;
    const int c  = t % CG;
    const int base = lb * 32;
    const float4* x4 = (const float4*)x;

    float acc[TR][4];
#pragma unroll
    for (int i = 0; i < TR; ++i)
#pragma unroll
        for (int j = 0; j < 4; ++j) acc[i][j] = 0.0f;

    for (int d4 = 0; d4 < DIN / 4; ++d4) {
        float4 xf[TR];
#pragma unroll
        for (int i = 0; i < TR; ++i)
            xf[i] = x4[(size_t)(base + rg * TR + i) * (DIN / 4) + d4];
        float4 wf[4];
#pragma unroll
        for (int dd = 0; dd < 4; ++dd)
            wf[dd] = *(const float4*)&sWt[4 * d4 + dd][4 * c];
#pragma unroll
        for (int i = 0; i < TR; ++i) {
            acc[i][0] += xf[i].x * wf[0].x + xf[i].y * wf[1].x + xf[i].z * wf[2].x + xf[i].w * wf[3].x;
            acc[i][1] += xf[i].x * wf[0].y + xf[i].y * wf[1].y + xf[i].z * wf[2].y + xf[i].w * wf[3].y;
            acc[i][2] += xf[i].x * wf[0].z + xf[i].y * wf[1].z + xf[i].z * wf[2].z + xf[i].w * wf[3].z;
            acc[i][3] += xf[i].x * wf[0].w + xf[i].y * wf[1].w + xf[i].z * wf[2].w + xf[i].w * wf[3].w;
        }
    }
#pragma unroll
    for (int i = 0; i < TR; ++i) {
        float4 o = {acc[i][0], acc[i][1], acc[i][2], acc[i][3]};
        ((float4*)out)[(size_t)(base + rg * TR + i) * CG + c] = o;
    }
}

// ---------------------------------------------------------------------------
// Kernel B: attn layer-1 (D=128, RELU) FUSED with linear2.
// Hot loop identical to the proven round-13 kernel (one query/wave, one
// batch/wave XCD-pinned, 16-lane DPP streams, skip-threshold flash update,
// depth-2 triple-buffer). Epilogue: x2 row -> LDS, one __syncthreads, then
// each wave computes its query's 64 h2 outputs (lane=col; W2 row k is 512B
// contiguous, L1-resident at 32KB). x2 never touches HBM; linear2 dispatch
// and its launch gap are eliminated.
// ---------------------------------------------------------------------------
__global__ __launch_bounds__(256) void k_attn1_lin2(
    const float* __restrict__ h, const int* __restrict__ cnt,
    const int* __restrict__ idx, const float* __restrict__ bias,
    const float* __restrict__ W2, float* __restrict__ h2out)
{
    constexpr int D  = DHID;
    constexpr int V  = D / 4;    // 32
    constexpr int NF = 2;        // float4s per lane
    constexpr int RB = D * 4;    // 512

    const int bid  = blockIdx.x;
    const int b    = bid & 7;
    const int wave = threadIdx.x >> 6;
    const int lane = threadIdx.x & 63;
    const int n    = (bid >> 3) * 4 + wave;
    const int grp  = lane >> 4;
    const int gl   = lane & 15;
    const int gtop = lane | 15;

    __shared__ int   s_off[4][MAXDEG + 16];
    __shared__ float s_x2[4][DHID];

    const int k = cnt[n];
    const int* __restrict__ myidx = idx + (size_t)n * MAXDEG;
    for (int j = lane; j < k; j += 64) s_off[wave][j] = myidx[j] * RB;
    if (lane < 16) s_off[wave][k + lane] = 0;

    const char* __restrict__ hb = (const char*)h + (size_t)b * N_ * RB;
    const int lb = gl * 16;

    float4 qf[NF];
#pragma unroll
    for (int i = 0; i < NF; ++i)
        qf[i] = *(const float4*)(hb + (size_t)n * RB + lb + 256 * i);

    float m;
    {
        float p = 0.0f;
#pragma unroll
        for (int i = 0; i < NF; ++i)
            p += qf[i].x * qf[i].x + qf[i].y * qf[i].y
               + qf[i].z * qf[i].z + qf[i].w * qf[i].w;
        p = dpp_reduce<16>(p);
        const float pb = __shfl(p, gtop, 64);
        m = (pb != 0.0f) ? pb : -INFINITY;
    }
    float mt = m - 100.0f;
    float s = 0.0f;
    float4 acc[NF];
#pragma unroll
    for (int i = 0; i < NF; ++i) acc[i] = {0.0f, 0.0f, 0.0f, 0.0f};

    auto loadrow = [&](float4 (&r)[NF], int j) {
        const char* hm = hb + s_off[wave][j];
#pragma unroll
        for (int i = 0; i < NF; ++i) r[i] = *(const float4*)(hm + lb + 256 * i);
    };
    auto process = [&](const float4 (&cur)[NF]) {
        float p = 0.0f;
#pragma unroll
        for (int i = 0; i < NF; ++i)
            p += qf[i].x * cur[i].x + qf[i].y * cur[i].y
               + qf[i].z * cur[i].z + qf[i].w * cur[i].w;
        p = dpp_reduce<16>(p);
        if (__builtin_expect((__ballot(p > mt) & 0x8000800080008000ULL) != 0ULL, 0)) {
            const float pb = __shfl(p, gtop, 64);
            const bool valid = (pb != 0.0f);
            const float pm   = valid ? pb : m;
            const float newm = fmaxf(m, pm);
            const float f = (m == newm) ? 1.0f : __expf(m - newm);
            const float e = valid ? __expf(pb - newm) : 0.0f;
            s = s * f + e;
#pragma unroll
            for (int i = 0; i < NF; ++i) {
                acc[i].x = acc[i].x * f + e * cur[i].x;
                acc[i].y = acc[i].y * f + e * cur[i].y;
                acc[i].z = acc[i].z * f + e * cur[i].z;
                acc[i].w = acc[i].w * f + e * cur[i].w;
            }
            m = newm;
            mt = m - 100.0f;
        }
    };

    {
        float4 r0[NF], r1[NF], r2[NF];
        loadrow(r0, grp);
        loadrow(r1, grp + 4);
        int j = grp;
        while (j < k) {
            loadrow(r2, j + 8);
            process(r0);
            j += 4; if (j >= k) break;
            loadrow(r0, j + 8);
            process(r1);
            j += 4; if (j >= k) break;
            loadrow(r1, j + 8);
            process(r2);
            j += 4;
        }
    }

#pragma unroll
    for (int mask = 16; mask <= 32; mask <<= 1) {
        const float m2 = __shfl_xor(m, mask, 64);
        const float s2 = __shfl_xor(s, mask, 64);
        float4 a2[NF];
#pragma unroll
        for (int i = 0; i < NF; ++i) {
            a2[i].x = __shfl_xor(acc[i].x, mask, 64);
            a2[i].y = __shfl_xor(acc[i].y, mask, 64);
            a2[i].z = __shfl_xor(acc[i].z, mask, 64);
            a2[i].w = __shfl_xor(acc[i].w, mask, 64);
        }
        const float mm = fmaxf(m, m2);
        const float f1 = (m  == mm) ? 1.0f : __expf(m  - mm);
        const float f2 = (m2 == mm) ? 1.0f : __expf(m2 - mm);
        s = s * f1 + s2 * f2;
#pragma unroll
        for (int i = 0; i < NF; ++i) {
            acc[i].x = acc[i].x * f1 + a2[i].x * f2;
            acc[i].y = acc[i].y * f1 + a2[i].y * f2;
            acc[i].z = acc[i].z * f1 + a2[i].z * f2;
            acc[i].w = acc[i].w * f1 + a2[i].w * f2;
        }
        m = mm;
    }

    // x2 row (relu(attn + b1)) -> LDS
    if (s > 0.0f) {
        if (grp == 0) {
            const float4* bias4 = (const float4*)bias;
            const float inv = 1.0f / s;
#pragma unroll
            for (int i = 0; i < NF; ++i) {
                const float4 bi = bias4[gl + 16 * i];
                float4 o;
                o.x = fmaxf(acc[i].x * inv + bi.x, 0.0f);
                o.y = fmaxf(acc[i].y * inv + bi.y, 0.0f);
                o.z = fmaxf(acc[i].z * inv + bi.z, 0.0f);
                o.w = fmaxf(acc[i].w * inv + bi.w, 0.0f);
                *(float4*)&s_x2[wave][4 * (gl + 16 * i)] = o;
            }
        }
    } else {
        // RARE: all masked -> column mean of h[b] (never taken w/ self-loop)
        const float4* hb4 = (const float4*)hb;
        const int sl = lane % V;
        const int rs = lane / V;
        float4 a = {0.0f, 0.0f, 0.0f, 0.0f};
        for (int row = rs; row < N_; row += 2) {
            float4 v = hb4[(size_t)row * V + sl];
            a.x += v.x; a.y += v.y; a.z += v.z; a.w += v.w;
        }
        a.x += __shfl_xor(a.x, 32, 64);
        a.y += __shfl_xor(a.y, 32, 64);
        a.z += __shfl_xor(a.z, 32, 64);
        a.w += __shfl_xor(a.w, 32, 64);
        if (lane < V) {
            constexpr float invN = 1.0f / (float)N_;
            const float4 bi = ((const float4*)bias)[sl];
            float4 o;
            o.x = fmaxf(a.x * invN + bi.x, 0.0f);
            o.y = fmaxf(a.y * invN + bi.y, 0.0f);
            o.z = fmaxf(a.z * invN + bi.z, 0.0f);
            o.w = fmaxf(a.w * invN + bi.w, 0.0f);
            *(float4*)&s_x2[wave][4 * sl] = o;
        }
    }
    __syncthreads();

    // fused linear2: h2[n, k] = sum_d x2[n, d] * W2[k, d]; lane = col k
    {
        const float4* w2r = (const float4*)(W2 + (size_t)lane * DHID);
        const float4* xr  = (const float4*)&s_x2[wave][0];
        float a0 = 0.0f, a1 = 0.0f;
#pragma unroll
        for (int d4 = 0; d4 < DHID / 8; ++d4) {
            float4 xv0 = xr[2 * d4],     wv0 = w2r[2 * d4];
            float4 xv1 = xr[2 * d4 + 1], wv1 = w2r[2 * d4 + 1];
            a0 += xv0.x * wv0.x + xv0.y * wv0.y + xv0.z * wv0.z + xv0.w * wv0.w;
            a1 += xv1.x * wv1.x + xv1.y * wv1.y + xv1.z * wv1.z + xv1.w * wv1.w;
        }
        h2out[((size_t)b * N_ + n) * DOUT2 + lane] = a0 + a1;
    }
}

// ---------------------------------------------------------------------------
// Kernel C: attn layer-2 (D=64, no relu) -- round-13 kernel, 8-lane streams.
// ---------------------------------------------------------------------------
__global__ __launch_bounds__(256) void k_attn2(
    const float* __restrict__ h, const int* __restrict__ cnt,
    const int* __restrict__ idx, const float* __restrict__ bias,
    float* __restrict__ out)
{
    constexpr int D  = DOUT2;
    constexpr int V  = D / 4;    // 16
    constexpr int NF = 2;
    constexpr int RB = D * 4;    // 256

    const int bid  = blockIdx.x;
    const int b    = bid & 7;
    const int wave = threadIdx.x >> 6;
    const int lane = threadIdx.x & 63;
    const int n    = (bid >> 3) * 4 + wave;
    const int grp  = lane >> 3;              // 8 streams
    const int gl   = lane & 7;
    const int gtop = lane | 7;

    __shared__ int s_off[4][MAXDEG + 16];

    const int k = cnt[n];
    const int* __restrict__ myidx = idx + (size_t)n * MAXDEG;
    for (int j = lane; j < k; j += 64) s_off[wave][j] = myidx[j] * RB;
    if (lane < 16) s_off[wave][k + lane] = 0;

    const char* __restrict__ hb = (const char*)h + (size_t)b * N_ * RB;
    const int lb = gl * 16;

    float4 qf[NF];
#pragma unroll
    for (int i = 0; i < NF; ++i)
        qf[i] = *(const float4*)(hb + (size_t)n * RB + lb + 128 * i);

    float m;
    {
        float p = 0.0f;
#pragma unroll
        for (int i = 0; i < NF; ++i)
            p += qf[i].x * qf[i].x + qf[i].y * qf[i].y
               + qf[i].z * qf[i].z + qf[i].w * qf[i].w;
        p = dpp_reduce<8>(p);
        const float pb = __shfl(p, gtop, 64);
        m = (pb != 0.0f) ? pb : -INFINITY;
    }
    float mt = m - 100.0f;
    float s = 0.0f;
    float4 acc[NF];
#pragma unroll
    for (int i = 0; i < NF; ++i) acc[i] = {0.0f, 0.0f, 0.0f, 0.0f};

    auto loadrow = [&](float4 (&r)[NF], int j) {
        const char* hm = hb + s_off[wave][j];
#pragma unroll
        for (int i = 0; i < NF; ++i) r[i] = *(const float4*)(hm + lb + 128 * i);
    };
    auto process = [&](const float4 (&cur)[NF]) {
        float p = 0.0f;
#pragma unroll
        for (int i = 0; i < NF; ++i)
            p += qf[i].x * cur[i].x + qf[i].y * cur[i].y
               + qf[i].z * cur[i].z + qf[i].w * cur[i].w;
        p = dpp_reduce<8>(p);
        if (__builtin_expect((__ballot(p > mt) & 0x8080808080808080ULL) != 0ULL, 0)) {
            const float pb = __shfl(p, gtop, 64);
            const bool valid = (pb != 0.0f);
            const float pm   = valid ? pb : m;
            const float newm = fmaxf(m, pm);
            const float f = (m == newm) ? 1.0f : __expf(m - newm);
            const float e = valid ? __expf(pb - newm) : 0.0f;
            s = s * f + e;
#pragma unroll
            for (int i = 0; i < NF; ++i) {
                acc[i].x = acc[i].x * f + e * cur[i].x;
                acc[i].y = acc[i].y * f + e * cur[i].y;
                acc[i].z = acc[i].z * f + e * cur[i].z;
                acc[i].w = acc[i].w * f + e * cur[i].w;
            }
            m = newm;
            mt = m - 100.0f;
        }
    };

    {
        float4 r0[NF], r1[NF], r2[NF];
        loadrow(r0, grp);
        loadrow(r1, grp + 8);
        int j = grp;
        while (j < k) {
            loadrow(r2, j + 16);
            process(r0);
            j += 8; if (j >= k) break;
            loadrow(r0, j + 16);
            process(r1);
            j += 8; if (j >= k) break;
            loadrow(r1, j + 16);
            process(r2);
            j += 8;
        }
    }

#pragma unroll
    for (int mask = 8; mask <= 32; mask <<= 1) {
        const float m2 = __shfl_xor(m, mask, 64);
        const float s2 = __shfl_xor(s, mask, 64);
        float4 a2[NF];
#pragma unroll
        for (int i = 0; i < NF; ++i) {
            a2[i].x = __shfl_xor(acc[i].x, mask, 64);
            a2[i].y = __shfl_xor(acc[i].y, mask, 64);
            a2[i].z = __shfl_xor(acc[i].z, mask, 64);
            a2[i].w = __shfl_xor(acc[i].w, mask, 64);
        }
        const float mm = fmaxf(m, m2);
        const float f1 = (m  == mm) ? 1.0f : __expf(m  - mm);
        const float f2 = (m2 == mm) ? 1.0f : __expf(m2 - mm);
        s = s * f1 + s2 * f2;
#pragma unroll
        for (int i = 0; i < NF; ++i) {
            acc[i].x = acc[i].x * f1 + a2[i].x * f2;
            acc[i].y = acc[i].y * f1 + a2[i].y * f2;
            acc[i].z = acc[i].z * f1 + a2[i].z * f2;
            acc[i].w = acc[i].w * f1 + a2[i].w * f2;
        }
        m = mm;
    }

    if (s > 0.0f) {
        if (grp == 0) {
            const float4* bias4 = (const float4*)bias;
            const float inv = 1.0f / s;
#pragma unroll
            for (int i = 0; i < NF; ++i) {
                const float4 bi = bias4[gl + 8 * i];
                float4 o;
                o.x = acc[i].x * inv + bi.x;
                o.y = acc[i].y * inv + bi.y;
                o.z = acc[i].z * inv + bi.z;
                o.w = acc[i].w * inv + bi.w;
                ((float4*)out)[((size_t)b * N_ + n) * V + gl + 8 * i] = o;
            }
        }
    } else {
        const float4* hb4 = (const float4*)hb;
        const int sl = lane % V;
        const int rs = lane / V;
        float4 a = {0.0f, 0.0f, 0.0f, 0.0f};
        for (int row = rs; row < N_; row += 4) {
            float4 v = hb4[(size_t)row * V + sl];
            a.x += v.x; a.y += v.y; a.z += v.z; a.w += v.w;
        }
#pragma unroll
        for (int mask = 16; mask <= 32; mask <<= 1) {
            a.x += __shfl_xor(a.x, mask, 64);
            a.y += __shfl_xor(a.y, mask, 64);
            a.z += __shfl_xor(a.z, mask, 64);
            a.w += __shfl_xor(a.w, mask, 64);
        }
        if (lane < V) {
            constexpr float invN = 1.0f / (float)N_;
            const float4 bi = ((const float4*)bias)[sl];
            float4 o;
            o.x = a.x * invN + bi.x;
            o.y = a.y * invN + bi.y;
            o.z = a.z * invN + bi.z;
            o.w = a.w * invN + bi.w;
            ((float4*)out)[((size_t)b * N_ + n) * V + sl] = o;
        }
    }
}

// ---------------------------------------------------------------------------
// Launch: 3 dispatches.
// ---------------------------------------------------------------------------
extern "C" void kernel_launch(void* const* d_in, const int* in_sizes, int n_in,
                              void* d_out, int out_size, void* d_ws, size_t ws_size,
                              hipStream_t stream) {
    (void)in_sizes; (void)n_in; (void)out_size; (void)ws_size;

    const float* flow_x = (const float*)d_in[0];
    const float* graph  = (const float*)d_in[1];
    const float* W1     = (const float*)d_in[2];
    const float* b1     = (const float*)d_in[3];
    const float* W2     = (const float*)d_in[4];
    const float* b2     = (const float*)d_in[5];
    float* out = (float*)d_out;

    char* p = (char*)d_ws;
    auto carve = [&](size_t bytes) -> void* {
        void* r = (void*)p;
        p += (bytes + 255) & ~(size_t)255;
        return r;
    };
    int*   nbr_cnt = (int*)carve((size_t)N_ * sizeof(int));
    int*   nbr_idx = (int*)carve((size_t)N_ * MAXDEG * sizeof(int));
    float* h1      = (float*)carve((size_t)B_ * N_ * DHID * sizeof(float));
    float* h2      = (float*)carve((size_t)B_ * N_ * DOUT2 * sizeof(float));

    // 1. CSR (blocks 0..1023) + linear1 (blocks 1024..2047), overlapped
    k_csr_linear<DIN1, DHID><<<N_ / 4 + (B_ * N_) / 32, 256, 0, stream>>>(
        graph, nbr_cnt, nbr_idx, flow_x, W1, h1);

    // 2. attn layer 1 (+bias+relu) fused with linear2 -> h2
    k_attn1_lin2<<<N_ * B_ / 4, 256, 0, stream>>>(h1, nbr_cnt, nbr_idx, b1, W2, h2);

    // 3. attn layer 2 (+bias) -> out  ([B,N,1,64] flat-identical)
    k_attn2<<<N_ * B_ / 4, 256, 0, stream>>>(h2, nbr_cnt, nbr_idx, b2, out);
}

// Round 15
// 269.895 us; speedup vs baseline: 1.3929x; 1.3929x over previous
//
#include <hip/hip_runtime.h>
#include <hip/hip_bf16.h>
#include <cmath>

// Problem constants
#define B_   8
#define N_   4096
#define DIN1 64
#define DHID 128
#define DOUT2 64
#define MAXDEG 256

template <int SH>
__device__ __forceinline__ float dpp_shr_add(float p) {
    int t = __builtin_amdgcn_update_dpp(0, __float_as_int(p),
                                        0x110 | SH, 0xF, 0xF, true);
    return p + __int_as_float(t);
}
// Row-sum lands on the TOP lane of each GRPL-lane subgroup (row_shr moves
// values toward higher lanes; tops of 8-lane halves stay uncontaminated).
template <int GRPL>
__device__ __forceinline__ float dpp_reduce(float p) {
    if constexpr (GRPL == 16) p = dpp_shr_add<8>(p);
    p = dpp_shr_add<4>(p);
    p = dpp_shr_add<2>(p);
    p = dpp_shr_add<1>(p);
    return p;   // valid on lane GRPL-1 of each subgroup
}

// ---------------------------------------------------------------------------
// Kernel 1: adjacency -> neighbor lists. One WAVE per row; ballot+popc
// compaction (no LDS, no atomics, no barriers).  [R13-proven]
// ---------------------------------------------------------------------------
__global__ __launch_bounds__(256) void k_build_csr(
    const float* __restrict__ graph, int* __restrict__ cnt, int* __restrict__ idx)
{
    const int wave = threadIdx.x >> 6;
    const int lane = threadIdx.x & 63;
    const int n = blockIdx.x * 4 + wave;
    const unsigned long long below_mask = (1ULL << lane) - 1ULL;

    const float4* __restrict__ row4 = (const float4*)(graph + (size_t)n * N_);
    int* __restrict__ myidx = idx + (size_t)n * MAXDEG;

    int base = 0;
    for (int it = 0; it < N_ / 256; ++it) {      // 16 iterations
        const int i4 = it * 64 + lane;
        float4 g = row4[i4];
        const int e = 4 * i4;
#pragma unroll
        for (int c = 0; c < 4; ++c) {
            const float gc = (c == 0) ? g.x : (c == 1) ? g.y : (c == 2) ? g.z : g.w;
            const unsigned long long mk = __ballot(gc != 0.0f);
            const int pos = base + __popcll(mk & below_mask);
            if (gc != 0.0f && pos < MAXDEG) myidx[pos] = e + c;
            base += __popcll(mk);                // wave-uniform
        }
    }
    if (lane == 0) cnt[n] = (base < MAXDEG) ? base : MAXDEG;
}

// ---------------------------------------------------------------------------
// Kernel 2: register-tiled linear. out[r,k] = sum_d x[r,d]*W[k,d]. [R13]
// ---------------------------------------------------------------------------
template <int DIN, int DOUT>
__global__ __launch_bounds__(256) void k_linear(
    const float* __restrict__ x, const float* __restrict__ W,
    float* __restrict__ out)
{
    constexpr int CG = DOUT / 4;
    constexpr int RG = 256 / CG;
    constexpr int TR = 32 / RG;

    __shared__ float sWt[DIN][DOUT + 4];

    const int t = threadIdx.x;
    const float4* W4 = (const float4*)W;
    for (int i = t; i < DOUT * (DIN / 4); i += 256) {
        int kk = i / (DIN / 4);
        int d4 = i % (DIN / 4);
        float4 w = W4[i];
        sWt[4 * d4 + 0][kk] = w.x;
        sWt[4 * d4 + 1][kk] = w.y;
        sWt[4 * d4 + 2][kk] = w.z;
        sWt[4 * d4 + 3][kk] = w.w;
    }
    __syncthreads();

    const int rg = t / CG;
    const int c  = t % CG;
    const int base = blockIdx.x * 32;
    const float4* x4 = (const float4*)x;

    float acc[TR][4];
#pragma unroll
    for (int i = 0; i < TR; ++i)
#pragma unroll
        for (int j = 0; j < 4; ++j) acc[i][j] = 0.0f;

    for (int d4 = 0; d4 < DIN / 4; ++d4) {
        float4 xf[TR];
#pragma unroll
        for (int i = 0; i < TR; ++i)
            xf[i] = x4[(size_t)(base + rg * TR + i) * (DIN / 4) + d4];
        float4 wf[4];
#pragma unroll
        for (int dd = 0; dd < 4; ++dd)
            wf[dd] = *(const float4*)&sWt[4 * d4 + dd][4 * c];
#pragma unroll
        for (int i = 0; i < TR; ++i) {
            acc[i][0] += xf[i].x * wf[0].x + xf[i].y * wf[1].x + xf[i].z * wf[2].x + xf[i].w * wf[3].x;
            acc[i][1] += xf[i].x * wf[0].y + xf[i].y * wf[1].y + xf[i].z * wf[2].y + xf[i].w * wf[3].y;
            acc[i][2] += xf[i].x * wf[0].z + xf[i].y * wf[1].z + xf[i].z * wf[2].z + xf[i].w * wf[3].z;
            acc[i][3] += xf[i].x * wf[0].w + xf[i].y * wf[1].w + xf[i].z * wf[2].w + xf[i].w * wf[3].w;
        }
    }

#pragma unroll
    for (int i = 0; i < TR; ++i) {
        float4 o = {acc[i][0], acc[i][1], acc[i][2], acc[i][3]};
        ((float4*)out)[(size_t)(base + rg * TR + i) * CG + c] = o;
    }
}

// ---------------------------------------------------------------------------
// Kernel 3: online-softmax sparse masked attention (R13 structure) with an
// OFFSET PIPELINE: 3 offset registers fetched 4 GS-slots ahead (period-3,
// zero moves) so every global gather consumes a register-resident offset --
// the ds_read(s_off) -> global_load dependency chain (~120cyc LGKM gate,
// the one latency component never yet varied) is buried 2+ iterations deep.
// s_off zero-padded to k+48 -> all overshoot reads/loads are guard-free.
// One query/wave, one batch/wave (XCD L2 pinning, proven R12). GRPL=16 for
// D=128, 8 for D=64. DPP subgroup reduce; wave-uniform ballot skip (terms
// with p <= m-100 underflow exp to exactly 0 -> bit-neutral skip); taken
// path = exact two-sided flash update. Exact torch masked_fill(s==0)
// semantics; all-masked uniform-softmax fallback = rare in-kernel path.
// ---------------------------------------------------------------------------
template <int D, bool RELU>
__global__ __launch_bounds__(256) void k_attn(
    const float* __restrict__ h, const int* __restrict__ cnt,
    const int* __restrict__ idx, const float* __restrict__ bias,
    float* __restrict__ out)
{
    constexpr int V    = D / 4;                  // float4s per row
    constexpr int GRPL = (D == 128) ? 16 : 8;    // lanes per stream
    constexpr int GS   = 64 / GRPL;              // streams per wave (4 or 8)
    constexpr int NF   = V / GRPL;               // float4s per lane (2)
    constexpr int RB   = D * 4;                  // row bytes
    const unsigned long long TOPMASK =
        (GRPL == 16) ? 0x8000800080008000ULL : 0x8080808080808080ULL;

    const int bid  = blockIdx.x;
    const int b    = bid & 7;                    // batch -> XCD pinning
    const int wave = threadIdx.x >> 6;
    const int lane = threadIdx.x & 63;
    const int n    = (bid >> 3) * 4 + wave;      // one query per wave
    const int grp  = lane / GRPL;
    const int gl   = lane % GRPL;
    const int gtop = lane | (GRPL - 1);          // subgroup TOP lane

    __shared__ int s_off[4][MAXDEG + 48];        // wave-private byte offsets

    const int k = cnt[n];
    const int* __restrict__ myidx = idx + (size_t)n * MAXDEG;
    for (int j = lane; j < k; j += 64) s_off[wave][j] = myidx[j] * RB;
    for (int z = k + lane; z < k + 48; z += 64) s_off[wave][z] = 0;  // pads

    const char* __restrict__ hb = (const char*)h + (size_t)b * N_ * RB;
    const int lb = gl * 16;                       // lane's byte slot in row

    float4 qf[NF];
#pragma unroll
    for (int i = 0; i < NF; ++i)
        qf[i] = *(const float4*)(hb + (size_t)n * RB + lb + GRPL * 16 * i);

    // self-score init: m = ||q||^2, broadcast from TOP lane (group-uniform)
    float m;
    {
        float p = 0.0f;
#pragma unroll
        for (int i = 0; i < NF; ++i)
            p += qf[i].x * qf[i].x + qf[i].y * qf[i].y
               + qf[i].z * qf[i].z + qf[i].w * qf[i].w;
        p = dpp_reduce<GRPL>(p);
        const float pb = __shfl(p, gtop, 64);
        m = (pb != 0.0f) ? pb : -INFINITY;
    }
    float mt = m - 100.0f;                       // skip threshold (uniform)
    float s = 0.0f;
    float4 acc[NF];
#pragma unroll
    for (int i = 0; i < NF; ++i) acc[i] = {0.0f, 0.0f, 0.0f, 0.0f};

    auto loadrow = [&](float4 (&r)[NF], int off) {
        const char* hm = hb + off;
#pragma unroll
        for (int i = 0; i < NF; ++i)
            r[i] = *(const float4*)(hm + lb + GRPL * 16 * i);
    };
    auto process = [&](const float4 (&cur)[NF]) {
        float p = 0.0f;
#pragma unroll
        for (int i = 0; i < NF; ++i)
            p += qf[i].x * cur[i].x + qf[i].y * cur[i].y
               + qf[i].z * cur[i].z + qf[i].w * cur[i].w;
        p = dpp_reduce<GRPL>(p);                  // TOP lane holds true sum
        if (__builtin_expect((__ballot(p > mt) & TOPMASK) != 0ULL, 0)) {
            const float pb = __shfl(p, gtop, 64); // true subgroup sum
            const bool valid = (pb != 0.0f);      // dot==0 => masked (torch)
            const float pm   = valid ? pb : m;
            const float newm = fmaxf(m, pm);
            const float f = (m == newm) ? 1.0f : __expf(m - newm);
            const float e = valid ? __expf(pb - newm) : 0.0f;
            s = s * f + e;
#pragma unroll
            for (int i = 0; i < NF; ++i) {
                acc[i].x = acc[i].x * f + e * cur[i].x;
                acc[i].y = acc[i].y * f + e * cur[i].y;
                acc[i].z = acc[i].z * f + e * cur[i].z;
                acc[i].w = acc[i].w * f + e * cur[i].w;
            }
            m = newm;
            mt = m - 100.0f;
        }
    };

    // depth-2 data pipeline + depth-4 OFFSET pipeline (period-3, no moves).
    // Invariant at leg for slot i: o_use=off(i+2), o_next=off(i+3);
    // leg fetches off(i+4), data-loads slot i+2, processes slot i.
    {
        float4 r0[NF], r1[NF], r2[NF];
        int oA = s_off[wave][grp + 2 * GS];      // off(2)
        int oB = s_off[wave][grp + 3 * GS];      // off(3)
        int oC;
        loadrow(r0, s_off[wave][grp]);           // data slot 0
        loadrow(r1, s_off[wave][grp + GS]);      // data slot 1
        int j = grp;
        while (j < k) {
            oC = s_off[wave][j + 4 * GS];        // off(i+4)
            loadrow(r2, oA);                     // data slot i+2
            process(r0);
            j += GS; if (j >= k) break;
            oA = s_off[wave][j + 4 * GS];
            loadrow(r0, oB);
            process(r1);
            j += GS; if (j >= k) break;
            oB = s_off[wave][j + 4 * GS];
            loadrow(r1, oC);
            process(r2);
            j += GS;
        }
    }

    // merge the GS subgroup states (xor GRPL..32); all 64 lanes converge
#pragma unroll
    for (int mask = GRPL; mask <= 32; mask <<= 1) {
        const float m2 = __shfl_xor(m, mask, 64);
        const float s2 = __shfl_xor(s, mask, 64);
        float4 a2[NF];
#pragma unroll
        for (int i = 0; i < NF; ++i) {
            a2[i].x = __shfl_xor(acc[i].x, mask, 64);
            a2[i].y = __shfl_xor(acc[i].y, mask, 64);
            a2[i].z = __shfl_xor(acc[i].z, mask, 64);
            a2[i].w = __shfl_xor(acc[i].w, mask, 64);
        }
        const float mm = fmaxf(m, m2);
        const float f1 = (m  == mm) ? 1.0f : __expf(m  - mm);  // -inf guard
        const float f2 = (m2 == mm) ? 1.0f : __expf(m2 - mm);
        s = s * f1 + s2 * f2;
#pragma unroll
        for (int i = 0; i < NF; ++i) {
            acc[i].x = acc[i].x * f1 + a2[i].x * f2;
            acc[i].y = acc[i].y * f1 + a2[i].y * f2;
            acc[i].z = acc[i].z * f1 + a2[i].z * f2;
            acc[i].w = acc[i].w * f1 + a2[i].w * f2;
        }
        m = mm;
    }

    if (s > 0.0f) {
        // normal epilogue: subgroup 0 writes the row
        if (grp == 0) {
            const float4* bias4 = (const float4*)bias;
            const float inv = 1.0f / s;
#pragma unroll
            for (int i = 0; i < NF; ++i) {
                const float4 bi = bias4[gl + GRPL * i];
                float4 o;
                o.x = acc[i].x * inv + bi.x;
                o.y = acc[i].y * inv + bi.y;
                o.z = acc[i].z * inv + bi.z;
                o.w = acc[i].w * inv + bi.w;
                if (RELU) {
                    o.x = fmaxf(o.x, 0.0f); o.y = fmaxf(o.y, 0.0f);
                    o.z = fmaxf(o.z, 0.0f); o.w = fmaxf(o.w, 0.0f);
                }
                ((float4*)out)[((size_t)b * N_ + n) * V + gl + GRPL * i] = o;
            }
        }
    } else {
        // RARE path (all scores masked): uniform softmax over all N rows ->
        // column mean of h[b]. Never taken unless the whole q row is zero.
        const float4* hb4 = (const float4*)hb;
        constexpr int RS = 64 / V;
        const int sl = lane % V;
        const int rs = lane / V;
        float4 a = {0.0f, 0.0f, 0.0f, 0.0f};
        for (int row = rs; row < N_; row += RS) {
            float4 v = hb4[(size_t)row * V + sl];
            a.x += v.x; a.y += v.y; a.z += v.z; a.w += v.w;
        }
#pragma unroll
        for (int mask = V; mask < 64; mask <<= 1) {
            a.x += __shfl_xor(a.x, mask, 64);
            a.y += __shfl_xor(a.y, mask, 64);
            a.z += __shfl_xor(a.z, mask, 64);
            a.w += __shfl_xor(a.w, mask, 64);
        }
        if (lane < V) {
            constexpr float invN = 1.0f / (float)N_;
            const float4 bi = ((const float4*)bias)[sl];
            float4 o;
            o.x = a.x * invN + bi.x;
            o.y = a.y * invN + bi.y;
            o.z = a.z * invN + bi.z;
            o.w = a.w * invN + bi.w;
            if (RELU) {
                o.x = fmaxf(o.x, 0.0f); o.y = fmaxf(o.y, 0.0f);
                o.z = fmaxf(o.z, 0.0f); o.w = fmaxf(o.w, 0.0f);
            }
            ((float4*)out)[((size_t)b * N_ + n) * V + sl] = o;
        }
    }
}

// ---------------------------------------------------------------------------
// Launch (R13 structure: 5 dispatches, all standalone proven kernels)
// ---------------------------------------------------------------------------
extern "C" void kernel_launch(void* const* d_in, const int* in_sizes, int n_in,
                              void* d_out, int out_size, void* d_ws, size_t ws_size,
                              hipStream_t stream) {
    (void)in_sizes; (void)n_in; (void)out_size; (void)ws_size;

    const float* flow_x = (const float*)d_in[0];
    const float* graph  = (const float*)d_in[1];
    const float* W1     = (const float*)d_in[2];
    const float* b1     = (const float*)d_in[3];
    const float* W2     = (const float*)d_in[4];
    const float* b2     = (const float*)d_in[5];
    float* out = (float*)d_out;

    char* p = (char*)d_ws;
    auto carve = [&](size_t bytes) -> void* {
        void* r = (void*)p;
        p += (bytes + 255) & ~(size_t)255;
        return r;
    };
    int*   nbr_cnt = (int*)carve((size_t)N_ * sizeof(int));
    int*   nbr_idx = (int*)carve((size_t)N_ * MAXDEG * sizeof(int));
    float* h1      = (float*)carve((size_t)B_ * N_ * DHID * sizeof(float));
    float* x2      = (float*)carve((size_t)B_ * N_ * DHID * sizeof(float));
    float* h2      = (float*)carve((size_t)B_ * N_ * DOUT2 * sizeof(float));

    // 1. adjacency -> neighbor lists (wave-per-row ballot compaction)
    k_build_csr<<<N_ / 4, 256, 0, stream>>>(graph, nbr_cnt, nbr_idx);

    // 2. layer 1 linear
    k_linear<DIN1, DHID><<<(B_ * N_) / 32, 256, 0, stream>>>(flow_x, W1, h1);

    // 3. layer 1 attention + bias + relu
    k_attn<DHID, true><<<N_ * B_ / 4, 256, 0, stream>>>(h1, nbr_cnt, nbr_idx, b1, x2);

    // 4. layer 2 linear
    k_linear<DHID, DOUT2><<<(B_ * N_) / 32, 256, 0, stream>>>(x2, W2, h2);

    // 5. layer 2 attention + bias -> d_out  ([B,N,1,64] flat-identical)
    k_attn<DOUT2, false><<<N_ * B_ / 4, 256, 0, stream>>>(h2, nbr_cnt, nbr_idx, b2, out);
}

// Round 17
// 239.954 us; speedup vs baseline: 1.5667x; 1.1248x over previous
//
#include <hip/hip_runtime.h>
#include <hip/hip_bf16.h>
#include <cmath>

// Problem constants
#define B_   8
#define N_   4096
#define DIN1 64
#define DHID 128
#define DOUT2 64
#define MAXDEG 256

// ---------------- bf16 helpers (RNE pack, shift unpack) --------------------
__device__ __forceinline__ unsigned pack2bf(float a, float b) {
    unsigned ua = __float_as_uint(a), ub = __float_as_uint(b);
    ua = (ua + 0x7FFFu + ((ua >> 16) & 1u)) >> 16;
    ub = (ub + 0x7FFFu + ((ub >> 16) & 1u)) & 0xFFFF0000u;
    return ua | ub;          // lo half = a, hi half = b
}
__device__ __forceinline__ float2 unpack2bf(unsigned u) {
    return {__uint_as_float(u << 16), __uint_as_float(u & 0xFFFF0000u)};
}

template <int SH>
__device__ __forceinline__ float dpp_shr_add(float p) {
    int t = __builtin_amdgcn_update_dpp(0, __float_as_int(p),
                                        0x110 | SH, 0xF, 0xF, true);
    return p + __int_as_float(t);
}
// Row-sum lands on the TOP lane of each GRPL-lane subgroup.
template <int GRPL>
__device__ __forceinline__ float dpp_reduce(float p) {
    if constexpr (GRPL == 16) p = dpp_shr_add<8>(p);
    p = dpp_shr_add<4>(p);
    p = dpp_shr_add<2>(p);
    p = dpp_shr_add<1>(p);
    return p;   // valid on lane GRPL-1 of each subgroup
}

// ---------------------------------------------------------------------------
// Kernel 1: adjacency -> neighbor lists. Wave per row, ballot compaction.
// ---------------------------------------------------------------------------
__global__ __launch_bounds__(256) void k_build_csr(
    const float* __restrict__ graph, int* __restrict__ cnt, int* __restrict__ idx)
{
    const int wave = threadIdx.x >> 6;
    const int lane = threadIdx.x & 63;
    const int n = blockIdx.x * 4 + wave;
    const unsigned long long below_mask = (1ULL << lane) - 1ULL;

    const float4* __restrict__ row4 = (const float4*)(graph + (size_t)n * N_);
    int* __restrict__ myidx = idx + (size_t)n * MAXDEG;

    int base = 0;
    for (int it = 0; it < N_ / 256; ++it) {
        const int i4 = it * 64 + lane;
        float4 g = row4[i4];
        const int e = 4 * i4;
#pragma unroll
        for (int c = 0; c < 4; ++c) {
            const float gc = (c == 0) ? g.x : (c == 1) ? g.y : (c == 2) ? g.z : g.w;
            const unsigned long long mk = __ballot(gc != 0.0f);
            const int pos = base + __popcll(mk & below_mask);
            if (gc != 0.0f && pos < MAXDEG) myidx[pos] = e + c;
            base += __popcll(mk);
        }
    }
    if (lane == 0) cnt[n] = (base < MAXDEG) ? base : MAXDEG;
}

// ---------------------------------------------------------------------------
// Kernel 2a: linear1 with DUAL WRITE: fp32 h1 (exact, for attn1's accumulate
// + layers downstream) and bf16 h1b (for attn1's gather/score hot loop).
// ---------------------------------------------------------------------------
__global__ __launch_bounds__(256) void k_linear1(
    const float* __restrict__ x, const float* __restrict__ W,
    float* __restrict__ out, void* __restrict__ outb)
{
    constexpr int DIN = DIN1, DOUT = DHID;
    constexpr int CG = DOUT / 4;      // 32
    constexpr int RG = 256 / CG;      // 8
    constexpr int TR = 32 / RG;       // 4

    __shared__ float sWt[DIN][DOUT + 4];

    const int t = threadIdx.x;
    const float4* W4 = (const float4*)W;
    for (int i = t; i < DOUT * (DIN / 4); i += 256) {
        int kk = i / (DIN / 4);
        int d4 = i % (DIN / 4);
        float4 w = W4[i];
        sWt[4 * d4 + 0][kk] = w.x;
        sWt[4 * d4 + 1][kk] = w.y;
        sWt[4 * d4 + 2][kk] = w.z;
        sWt[4 * d4 + 3][kk] = w.w;
    }
    __syncthreads();

    const int rg = t / CG;
    const int c  = t % CG;
    const int base = blockIdx.x * 32;
    const float4* x4 = (const float4*)x;

    float acc[TR][4];
#pragma unroll
    for (int i = 0; i < TR; ++i)
#pragma unroll
        for (int j = 0; j < 4; ++j) acc[i][j] = 0.0f;

    for (int d4 = 0; d4 < DIN / 4; ++d4) {
        float4 xf[TR];
#pragma unroll
        for (int i = 0; i < TR; ++i)
            xf[i] = x4[(size_t)(base + rg * TR + i) * (DIN / 4) + d4];
        float4 wf[4];
#pragma unroll
        for (int dd = 0; dd < 4; ++dd)
            wf[dd] = *(const float4*)&sWt[4 * d4 + dd][4 * c];
#pragma unroll
        for (int i = 0; i < TR; ++i) {
            acc[i][0] += xf[i].x * wf[0].x + xf[i].y * wf[1].x + xf[i].z * wf[2].x + xf[i].w * wf[3].x;
            acc[i][1] += xf[i].x * wf[0].y + xf[i].y * wf[1].y + xf[i].z * wf[2].y + xf[i].w * wf[3].y;
            acc[i][2] += xf[i].x * wf[0].z + xf[i].y * wf[1].z + xf[i].z * wf[2].z + xf[i].w * wf[3].z;
            acc[i][3] += xf[i].x * wf[0].w + xf[i].y * wf[1].w + xf[i].z * wf[2].w + xf[i].w * wf[3].w;
        }
    }

#pragma unroll
    for (int i = 0; i < TR; ++i) {
        const size_t row = (size_t)(base + rg * TR + i);
        float4 o = {acc[i][0], acc[i][1], acc[i][2], acc[i][3]};
        ((float4*)out)[row * CG + c] = o;
        uint2 ob = {pack2bf(o.x, o.y), pack2bf(o.z, o.w)};
        *(uint2*)((char*)outb + row * (DOUT * 2) + c * 8) = ob;
    }
}

// ---------------------------------------------------------------------------
// Kernel 2b: plain fp32 register-tiled linear (layer 2). [R15-proven]
// ---------------------------------------------------------------------------
template <int DIN, int DOUT>
__global__ __launch_bounds__(256) void k_linear(
    const float* __restrict__ x, const float* __restrict__ W,
    float* __restrict__ out)
{
    constexpr int CG = DOUT / 4;
    constexpr int RG = 256 / CG;
    constexpr int TR = 32 / RG;

    __shared__ float sWt[DIN][DOUT + 4];

    const int t = threadIdx.x;
    const float4* W4 = (const float4*)W;
    for (int i = t; i < DOUT * (DIN / 4); i += 256) {
        int kk = i / (DIN / 4);
        int d4 = i % (DIN / 4);
        float4 w = W4[i];
        sWt[4 * d4 + 0][kk] = w.x;
        sWt[4 * d4 + 1][kk] = w.y;
        sWt[4 * d4 + 2][kk] = w.z;
        sWt[4 * d4 + 3][kk] = w.w;
    }
    __syncthreads();

    const int rg = t / CG;
    const int c  = t % CG;
    const int base = blockIdx.x * 32;
    const float4* x4 = (const float4*)x;

    float acc[TR][4];
#pragma unroll
    for (int i = 0; i < TR; ++i)
#pragma unroll
        for (int j = 0; j < 4; ++j) acc[i][j] = 0.0f;

    for (int d4 = 0; d4 < DIN / 4; ++d4) {
        float4 xf[TR];
#pragma unroll
        for (int i = 0; i < TR; ++i)
            xf[i] = x4[(size_t)(base + rg * TR + i) * (DIN / 4) + d4];
        float4 wf[4];
#pragma unroll
        for (int dd = 0; dd < 4; ++dd)
            wf[dd] = *(const float4*)&sWt[4 * d4 + dd][4 * c];
#pragma unroll
        for (int i = 0; i < TR; ++i) {
            acc[i][0] += xf[i].x * wf[0].x + xf[i].y * wf[1].x + xf[i].z * wf[2].x + xf[i].w * wf[3].x;
            acc[i][1] += xf[i].x * wf[0].y + xf[i].y * wf[1].y + xf[i].z * wf[2].y + xf[i].w * wf[3].y;
            acc[i][2] += xf[i].x * wf[0].z + xf[i].y * wf[1].z + xf[i].z * wf[2].z + xf[i].w * wf[3].z;
            acc[i][3] += xf[i].x * wf[0].w + xf[i].y * wf[1].w + xf[i].z * wf[2].w + xf[i].w * wf[3].w;
        }
    }

#pragma unroll
    for (int i = 0; i < TR; ++i) {
        float4 o = {acc[i][0], acc[i][1], acc[i][2], acc[i][3]};
        ((float4*)out)[(size_t)(base + rg * TR + i) * CG + c] = o;
    }
}

// ---------------------------------------------------------------------------
// Kernel 3a: attn layer-1, BF16-GATHER / FP32-ACCUMULATE.
// Hot loop gathers bf16 rows (1 uint4/lane = full 128-dim row per 16-lane
// subgroup: lane-addresses and L2 bytes HALVE vs fp32 -- the R15 TA bound).
// Scores from bf16 (layer-1 self-vs-cross gap ~4000 >> +-30 bf16 noise, so
// max/skip decisions are unchanged); the RARE taken path (~1-2 per query)
// re-loads the row FP32 and accumulates exactly. Self term: p==m bit-exact
// (same bf16 values, same op order as m's init) -> e=1 -> x2 output is
// bit-identical to the passing R15 fp32 kernel under one-hot softmax.
// Exact torch masked_fill(s==0) semantics; all-masked fallback (fp32) rare.
// ---------------------------------------------------------------------------
__global__ __launch_bounds__(256) void k_attn1(
    const void* __restrict__ h16, const float* __restrict__ h32,
    const int* __restrict__ cnt, const int* __restrict__ idx,
    const float* __restrict__ bias, float* __restrict__ out)
{
    constexpr int RBb = DHID * 2;   // bf16 row bytes (256)
    constexpr int RBf = DHID * 4;   // fp32 row bytes (512)
    constexpr int GS  = 4;          // 4 streams of 16 lanes

    const int bid  = blockIdx.x;
    const int b    = bid & 7;                    // batch -> XCD pinning
    const int wave = threadIdx.x >> 6;
    const int lane = threadIdx.x & 63;
    const int n    = (bid >> 3) * 4 + wave;      // one query per wave
    const int grp  = lane >> 4;
    const int gl   = lane & 15;
    const int gtop = lane | 15;

    __shared__ int s_off[4][MAXDEG + 48];        // bf16 byte offsets

    const int k = cnt[n];
    const int* __restrict__ myidx = idx + (size_t)n * MAXDEG;
    for (int j = lane; j < k; j += 64) s_off[wave][j] = myidx[j] * RBb;
    for (int z = k + lane; z < k + 48; z += 64) s_off[wave][z] = 0;

    const char*  __restrict__ hb = (const char*)h16 + (size_t)b * N_ * RBb;
    const char*  __restrict__ hf = (const char*)h32 + (size_t)b * N_ * RBf;
    const int lb = gl * 16;                      // lane's bf16 byte slot

    // q fragment: 8 dims per lane, unpacked bf16 -> fp32
    float qc[8];
    {
        const uint4 qu = *(const uint4*)(hb + (size_t)n * RBb + lb);
        float2 t0 = unpack2bf(qu.x), t1 = unpack2bf(qu.y);
        float2 t2 = unpack2bf(qu.z), t3 = unpack2bf(qu.w);
        qc[0] = t0.x; qc[1] = t0.y; qc[2] = t1.x; qc[3] = t1.y;
        qc[4] = t2.x; qc[5] = t2.y; qc[6] = t3.x; qc[7] = t3.y;
    }

    // self-score init: m = ||q_bf16||^2 (identical op order to loop dot)
    float m;
    {
        float p = 0.0f;
#pragma unroll
        for (int i = 0; i < 8; ++i) p += qc[i] * qc[i];
        p = dpp_reduce<16>(p);
        const float pb = __shfl(p, gtop, 64);
        m = (pb != 0.0f) ? pb : -INFINITY;
    }
    float mt = m - 100.0f;
    float s = 0.0f;
    float acc8[8];
#pragma unroll
    for (int i = 0; i < 8; ++i) acc8[i] = 0.0f;

    // taken path accumulates from the FP32 row (off is the bf16 offset;
    // fp32 offset = 2*off since RBf = 2*RBb)
    auto process = [&](const uint4 cur, int off) {
        float2 t0 = unpack2bf(cur.x), t1 = unpack2bf(cur.y);
        float2 t2 = unpack2bf(cur.z), t3 = unpack2bf(cur.w);
        float c8[8] = {t0.x, t0.y, t1.x, t1.y, t2.x, t2.y, t3.x, t3.y};
        float p = 0.0f;
#pragma unroll
        for (int i = 0; i < 8; ++i) p += qc[i] * c8[i];
        p = dpp_reduce<16>(p);
        if (__builtin_expect((__ballot(p > mt) & 0x8000800080008000ULL) != 0ULL, 0)) {
            const float pb = __shfl(p, gtop, 64);
            const bool valid = (pb != 0.0f);      // dot==0 => masked (torch)
            const float pm   = valid ? pb : m;
            const float newm = fmaxf(m, pm);
            const float f = (m == newm) ? 1.0f : __expf(m - newm);
            const float e = valid ? __expf(pb - newm) : 0.0f;
            s = s * f + e;
            // fp32 reload of this row's lane slice (dims [8gl, 8gl+8))
            const float4* fr = (const float4*)(hf + 2 * (size_t)off) + 2 * gl;
            const float4 lo = fr[0], hi = fr[1];
            const float f8[8] = {lo.x, lo.y, lo.z, lo.w, hi.x, hi.y, hi.z, hi.w};
#pragma unroll
            for (int i = 0; i < 8; ++i) acc8[i] = acc8[i] * f + e * f8[i];
            m = newm;
            mt = m - 100.0f;
        }
    };

    // depth-2 data + depth-4 offset pipeline; per-buffer offsets carried
    {
        uint4 r0, r1, r2;
        int u0, u1, u2, oA, oB, oC;
        oA = s_off[wave][grp + 2 * GS];
        oB = s_off[wave][grp + 3 * GS];
        u0 = s_off[wave][grp];
        r0 = *(const uint4*)(hb + u0 + lb);
        u1 = s_off[wave][grp + GS];
        r1 = *(const uint4*)(hb + u1 + lb);
        int j = grp;
        while (j < k) {
            oC = s_off[wave][j + 4 * GS];
            u2 = oA; r2 = *(const uint4*)(hb + u2 + lb);
            process(r0, u0);
            j += GS; if (j >= k) break;
            oA = s_off[wave][j + 4 * GS];
            u0 = oB; r0 = *(const uint4*)(hb + u0 + lb);
            process(r1, u1);
            j += GS; if (j >= k) break;
            oB = s_off[wave][j + 4 * GS];
            u1 = oC; r1 = *(const uint4*)(hb + u1 + lb);
            process(r2, u2);
            j += GS;
        }
    }

    // merge the 4 subgroup states (xor 16, 32)
#pragma unroll
    for (int mask = 16; mask <= 32; mask <<= 1) {
        const float m2 = __shfl_xor(m, mask, 64);
        const float s2 = __shfl_xor(s, mask, 64);
        float a2[8];
#pragma unroll
        for (int i = 0; i < 8; ++i) a2[i] = __shfl_xor(acc8[i], mask, 64);
        const float mm = fmaxf(m, m2);
        const float f1 = (m  == mm) ? 1.0f : __expf(m  - mm);
        const float f2 = (m2 == mm) ? 1.0f : __expf(m2 - mm);
        s = s * f1 + s2 * f2;
#pragma unroll
        for (int i = 0; i < 8; ++i) acc8[i] = acc8[i] * f1 + a2[i] * f2;
        m = mm;
    }

    if (s > 0.0f) {
        if (grp == 0) {
            const float4* bias4 = (const float4*)bias;
            const float4 b0 = bias4[2 * gl], b1 = bias4[2 * gl + 1];
            const float bi[8] = {b0.x, b0.y, b0.z, b0.w, b1.x, b1.y, b1.z, b1.w};
            const float inv = 1.0f / s;
            float4 lo, hi;
            lo.x = fmaxf(acc8[0] * inv + bi[0], 0.0f);
            lo.y = fmaxf(acc8[1] * inv + bi[1], 0.0f);
            lo.z = fmaxf(acc8[2] * inv + bi[2], 0.0f);
            lo.w = fmaxf(acc8[3] * inv + bi[3], 0.0f);
            hi.x = fmaxf(acc8[4] * inv + bi[4], 0.0f);
            hi.y = fmaxf(acc8[5] * inv + bi[5], 0.0f);
            hi.z = fmaxf(acc8[6] * inv + bi[6], 0.0f);
            hi.w = fmaxf(acc8[7] * inv + bi[7], 0.0f);
            float4* orow = (float4*)out + ((size_t)b * N_ + n) * (DHID / 4) + 2 * gl;
            orow[0] = lo;
            orow[1] = hi;
        }
    } else {
        // RARE (all masked): uniform softmax -> column mean of fp32 h[b]
        const float4* hf4 = (const float4*)hf;
        const int sl = lane % 32;
        const int rs = lane / 32;
        float4 a = {0.0f, 0.0f, 0.0f, 0.0f};
        for (int row = rs; row < N_; row += 2) {
            float4 v = hf4[(size_t)row * 32 + sl];
            a.x += v.x; a.y += v.y; a.z += v.z; a.w += v.w;
        }
        a.x += __shfl_xor(a.x, 32, 64);
        a.y += __shfl_xor(a.y, 32, 64);
        a.z += __shfl_xor(a.z, 32, 64);
        a.w += __shfl_xor(a.w, 32, 64);
        if (lane < 32) {
            constexpr float invN = 1.0f / (float)N_;
            const float4 bi = ((const float4*)bias)[sl];
            float4 o;
            o.x = fmaxf(a.x * invN + bi.x, 0.0f);
            o.y = fmaxf(a.y * invN + bi.y, 0.0f);
            o.z = fmaxf(a.z * invN + bi.z, 0.0f);
            o.w = fmaxf(a.w * invN + bi.w, 0.0f);
            ((float4*)out)[((size_t)b * N_ + n) * 32 + sl] = o;
        }
    }
}

// ---------------------------------------------------------------------------
// Kernel 3b: attn layer-2, pure fp32 (R15-proven, D=64, 8-lane streams).
// ---------------------------------------------------------------------------
__global__ __launch_bounds__(256) void k_attn2(
    const float* __restrict__ h, const int* __restrict__ cnt,
    const int* __restrict__ idx, const float* __restrict__ bias,
    float* __restrict__ out)
{
    constexpr int D  = DOUT2;
    constexpr int V  = D / 4;                    // 16
    constexpr int GS = 8;                        // 8 streams of 8 lanes
    constexpr int RB = D * 4;                    // 256

    const int bid  = blockIdx.x;
    const int b    = bid & 7;
    const int wave = threadIdx.x >> 6;
    const int lane = threadIdx.x & 63;
    const int n    = (bid >> 3) * 4 + wave;
    const int grp  = lane >> 3;
    const int gl   = lane & 7;
    const int gtop = lane | 7;

    __shared__ int s_off[4][MAXDEG + 48];

    const int k = cnt[n];
    const int* __restrict__ myidx = idx + (size_t)n * MAXDEG;
    for (int j = lane; j < k; j += 64) s_off[wave][j] = myidx[j] * RB;
    for (int z = k + lane; z < k + 48; z += 64) s_off[wave][z] = 0;

    const char* __restrict__ hb = (const char*)h + (size_t)b * N_ * RB;
    const int lb = gl * 16;

    float4 qf[2];
#pragma unroll
    for (int i = 0; i < 2; ++i)
        qf[i] = *(const float4*)(hb + (size_t)n * RB + lb + 128 * i);

    float m;
    {
        float p = 0.0f;
#pragma unroll
        for (int i = 0; i < 2; ++i)
            p += qf[i].x * qf[i].x + qf[i].y * qf[i].y
               + qf[i].z * qf[i].z + qf[i].w * qf[i].w;
        p = dpp_reduce<8>(p);
        const float pb = __shfl(p, gtop, 64);
        m = (pb != 0.0f) ? pb : -INFINITY;
    }
    float mt = m - 100.0f;
    float s = 0.0f;
    float4 acc[2];
#pragma unroll
    for (int i = 0; i < 2; ++i) acc[i] = {0.0f, 0.0f, 0.0f, 0.0f};

    auto loadrow = [&](float4 (&r)[2], int off) {
        const char* hm = hb + off;
#pragma unroll
        for (int i = 0; i < 2; ++i) r[i] = *(const float4*)(hm + lb + 128 * i);
    };
    auto process = [&](const float4 (&cur)[2]) {
        float p = 0.0f;
#pragma unroll
        for (int i = 0; i < 2; ++i)
            p += qf[i].x * cur[i].x + qf[i].y * cur[i].y
               + qf[i].z * cur[i].z + qf[i].w * cur[i].w;
        p = dpp_reduce<8>(p);
        if (__builtin_expect((__ballot(p > mt) & 0x8080808080808080ULL) != 0ULL, 0)) {
            const float pb = __shfl(p, gtop, 64);
            const bool valid = (pb != 0.0f);
            const float pm   = valid ? pb : m;
            const float newm = fmaxf(m, pm);
            const float f = (m == newm) ? 1.0f : __expf(m - newm);
            const float e = valid ? __expf(pb - newm) : 0.0f;
            s = s * f + e;
#pragma unroll
            for (int i = 0; i < 2; ++i) {
                acc[i].x = acc[i].x * f + e * cur[i].x;
                acc[i].y = acc[i].y * f + e * cur[i].y;
                acc[i].z = acc[i].z * f + e * cur[i].z;
                acc[i].w = acc[i].w * f + e * cur[i].w;
            }
            m = newm;
            mt = m - 100.0f;
        }
    };

    {
        float4 r0[2], r1[2], r2[2];
        int oA = s_off[wave][grp + 2 * GS];
        int oB = s_off[wave][grp + 3 * GS];
        int oC;
        loadrow(r0, s_off[wave][grp]);
        loadrow(r1, s_off[wave][grp + GS]);
        int j = grp;
        while (j < k) {
            oC = s_off[wave][j + 4 * GS];
            loadrow(r2, oA);
            process(r0);
            j += GS; if (j >= k) break;
            oA = s_off[wave][j + 4 * GS];
            loadrow(r0, oB);
            process(r1);
            j += GS; if (j >= k) break;
            oB = s_off[wave][j + 4 * GS];
            loadrow(r1, oC);
            process(r2);
            j += GS;
        }
    }

#pragma unroll
    for (int mask = 8; mask <= 32; mask <<= 1) {
        const float m2 = __shfl_xor(m, mask, 64);
        const float s2 = __shfl_xor(s, mask, 64);
        float4 a2[2];
#pragma unroll
        for (int i = 0; i < 2; ++i) {
            a2[i].x = __shfl_xor(acc[i].x, mask, 64);
            a2[i].y = __shfl_xor(acc[i].y, mask, 64);
            a2[i].z = __shfl_xor(acc[i].z, mask, 64);
            a2[i].w = __shfl_xor(acc[i].w, mask, 64);
        }
        const float mm = fmaxf(m, m2);
        const float f1 = (m  == mm) ? 1.0f : __expf(m  - mm);
        const float f2 = (m2 == mm) ? 1.0f : __expf(m2 - mm);
        s = s * f1 + s2 * f2;
#pragma unroll
        for (int i = 0; i < 2; ++i) {
            acc[i].x = acc[i].x * f1 + a2[i].x * f2;
            acc[i].y = acc[i].y * f1 + a2[i].y * f2;
            acc[i].z = acc[i].z * f1 + a2[i].z * f2;
            acc[i].w = acc[i].w * f1 + a2[i].w * f2;
        }
        m = mm;
    }

    if (s > 0.0f) {
        if (grp == 0) {
            const float4* bias4 = (const float4*)bias;
            const float inv = 1.0f / s;
#pragma unroll
            for (int i = 0; i < 2; ++i) {
                const float4 bi = bias4[gl + 8 * i];
                float4 o;
                o.x = acc[i].x * inv + bi.x;
                o.y = acc[i].y * inv + bi.y;
                o.z = acc[i].z * inv + bi.z;
                o.w = acc[i].w * inv + bi.w;
                ((float4*)out)[((size_t)b * N_ + n) * V + gl + 8 * i] = o;
            }
        }
    } else {
        const float4* hb4 = (const float4*)hb;
        const int sl = lane % V;
        const int rs = lane / V;
        float4 a = {0.0f, 0.0f, 0.0f, 0.0f};
        for (int row = rs; row < N_; row += 4) {
            float4 v = hb4[(size_t)row * V + sl];
            a.x += v.x; a.y += v.y; a.z += v.z; a.w += v.w;
        }
#pragma unroll
        for (int mask = 16; mask <= 32; mask <<= 1) {
            a.x += __shfl_xor(a.x, mask, 64);
            a.y += __shfl_xor(a.y, mask, 64);
            a.z += __shfl_xor(a.z, mask, 64);
            a.w += __shfl_xor(a.w, mask, 64);
        }
        if (lane < V) {
            constexpr float invN = 1.0f / (float)N_;
            const float4 bi = ((const float4*)bias)[sl];
            float4 o;
            o.x = a.x * invN + bi.x;
            o.y = a.y * invN + bi.y;
            o.z = a.z * invN + bi.z;
            o.w = a.w * invN + bi.w;
            ((float4*)out)[((size_t)b * N_ + n) * V + sl] = o;
        }
    }
}

// ---------------------------------------------------------------------------
// Launch
// ---------------------------------------------------------------------------
extern "C" void kernel_launch(void* const* d_in, const int* in_sizes, int n_in,
                              void* d_out, int out_size, void* d_ws, size_t ws_size,
                              hipStream_t stream) {
    (void)in_sizes; (void)n_in; (void)out_size; (void)ws_size;

    const float* flow_x = (const float*)d_in[0];
    const float* graph  = (const float*)d_in[1];
    const float* W1     = (const float*)d_in[2];
    const float* b1     = (const float*)d_in[3];
    const float* W2     = (const float*)d_in[4];
    const float* b2     = (const float*)d_in[5];
    float* out = (float*)d_out;

    char* p = (char*)d_ws;
    auto carve = [&](size_t bytes) -> void* {
        void* r = (void*)p;
        p += (bytes + 255) & ~(size_t)255;
        return r;
    };
    int*   nbr_cnt = (int*)carve((size_t)N_ * sizeof(int));
    int*   nbr_idx = (int*)carve((size_t)N_ * MAXDEG * sizeof(int));
    float* h1      = (float*)carve((size_t)B_ * N_ * DHID * sizeof(float));
    void*  h1b     = carve((size_t)B_ * N_ * DHID * 2);   // bf16 copy
    float* x2      = (float*)carve((size_t)B_ * N_ * DHID * sizeof(float));
    float* h2      = (float*)carve((size_t)B_ * N_ * DOUT2 * sizeof(float));

    // 1. adjacency -> neighbor lists
    k_build_csr<<<N_ / 4, 256, 0, stream>>>(graph, nbr_cnt, nbr_idx);

    // 2. layer 1 linear: fp32 h1 + bf16 h1b (dual write)
    k_linear1<<<(B_ * N_) / 32, 256, 0, stream>>>(flow_x, W1, h1, h1b);

    // 3. layer 1 attention: bf16 gather/score, fp32 accumulate -> fp32 x2
    k_attn1<<<N_ * B_ / 4, 256, 0, stream>>>(h1b, h1, nbr_cnt, nbr_idx, b1, x2);

    // 4. layer 2 linear (fp32)
    k_linear<DHID, DOUT2><<<(B_ * N_) / 32, 256, 0, stream>>>(x2, W2, h2);

    // 5. layer 2 attention (fp32) -> d_out  ([B,N,1,64] flat-identical)
    k_attn2<<<N_ * B_ / 4, 256, 0, stream>>>(h2, nbr_cnt, nbr_idx, b2, out);
}